// Round 1
// 233.656 us; speedup vs baseline: 1.0198x; 1.0198x over previous
//
#include <hip/hip_runtime.h>
#include <hip/hip_bf16.h>

typedef unsigned short u16;
typedef unsigned int   u32;

typedef __attribute__((ext_vector_type(8))) __bf16 bf16x8;
typedef __attribute__((ext_vector_type(4))) float  f32x4;

#define NN 4096
#define DD 128
#define EPS 1e-12f

#define KS 4            // split-K factor
#define BM 32           // rows per block
#define BK 128          // k per stage (was 64)
#define KPER (NN / KS)  // 1024
#define LDK 136         // padded LDS row stride (u16), 272 B (16B-aligned)

static __device__ __forceinline__ u16 f2bf(float f) {
    union { float f; u32 u; } v; v.f = f;
    u32 r = v.u + 0x7fffu + ((v.u >> 16) & 1u);   // round-to-nearest-even
    return (u16)(r >> 16);
}

// ---------------------------------------------------------------------------
// Edge kernel: 32 lanes per edge (2 edges per wave).
// val = exp(-||A[c]+case-A[t]||); atomicAdd att[t*N+c], normsum[t].
// ---------------------------------------------------------------------------
__global__ __launch_bounds__(256) void edge_kernel(
    const int* __restrict__ currents, const int* __restrict__ targets,
    const float* __restrict__ A, const float* __restrict__ cases,
    float* __restrict__ att, float* __restrict__ normsum, int E)
{
    int e = blockIdx.x * 8 + (threadIdx.x >> 5);
    if (e >= E) return;
    int l = threadIdx.x & 31;
    int c = currents[e];
    int t = targets[e];
    float4 h = *(const float4*)(A + (size_t)c * DD + l * 4);
    float4 g = *(const float4*)(A + (size_t)t * DD + l * 4);
    float4 q = *(const float4*)(cases + (size_t)e * DD + l * 4);
    float d0 = h.x + q.x - g.x;
    float d1 = h.y + q.y - g.y;
    float d2 = h.z + q.z - g.z;
    float d3 = h.w + q.w - g.w;
    float s = d0 * d0 + d1 * d1 + d2 * d2 + d3 * d3;
#pragma unroll
    for (int m = 16; m; m >>= 1) s += __shfl_xor(s, m, 64);
    if (l == 0) {
        float val = __expf(-__fsqrt_rn(s));
        atomicAdd(att + (size_t)t * NN + c, val);
        atomicAdd(normsum + t, val);
    }
}

// ---------------------------------------------------------------------------
// Transpose+convert: in [4096][128] fp32 -> out [128][4096] bf16
// ---------------------------------------------------------------------------
__global__ __launch_bounds__(256) void transpose_to_bf16(
    const float* __restrict__ in, u16* __restrict__ out)
{
    __shared__ __align__(16) u16 lds[128][40];
    const int k0 = blockIdx.x * 32;
    const int t = threadIdx.x;
#pragma unroll
    for (int i = 0; i < 4; ++i) {
        int f  = t + 256 * i;
        int kr = f >> 5;
        int n0 = (f & 31) * 4;
        float4 v = *(const float4*)(in + (size_t)(k0 + kr) * DD + n0);
        lds[n0 + 0][kr] = f2bf(v.x);
        lds[n0 + 1][kr] = f2bf(v.y);
        lds[n0 + 2][kr] = f2bf(v.z);
        lds[n0 + 3][kr] = f2bf(v.w);
    }
    __syncthreads();
    int n = t >> 1, h = t & 1;
    uint4 v0 = *(const uint4*)&lds[n][h * 16];
    uint4 v1 = *(const uint4*)&lds[n][h * 16 + 8];
    *(uint4*)(out + (size_t)n * NN + k0 + h * 16)     = v0;
    *(uint4*)(out + (size_t)n * NN + k0 + h * 16 + 8) = v1;
}

// ---------------------------------------------------------------------------
// Split-K skinny GEMM with 1-deep register pipeline:
//   part[ks] = Amat[m0:m0+32, ks*1024:(ks+1)*1024] @ B
// Amat fp32 (converted to bf16 in staging), BT bf16 [128][4096] (B^T).
// 512 threads = 8 waves; wave w covers n-cols w*16..w*16+15, both 16-row
// m-tiles. Grid (128, KS) -> 512 blocks = 2 blocks/CU, 16 waves/CU.
// Per iter: store prefetched regs->LDS, barrier, ISSUE next tile's global
// loads (96 B/thread in flight), MFMA current tile, barrier. HBM latency
// hides under the compute phase instead of serializing with it.
// ---------------------------------------------------------------------------
__global__ __launch_bounds__(512, 4) void gemm_splitk(
    const float* __restrict__ Amat,   // [4096][4096]
    const u16*   __restrict__ BT,     // [128][4096]
    float* __restrict__ part)         // [KS][4096][128]
{
    __shared__ __align__(16) u16 As[BM * LDK];   // 8.7 KB
    __shared__ __align__(16) u16 Bs[DD * LDK];   // 34.8 KB

    const int m0   = blockIdx.x * BM;
    const int ks   = blockIdx.y;
    const int kbeg = ks * KPER;
    const int t    = threadIdx.x;
    const int wave = t >> 6;
    const int lane = t & 63;
    const int quad = lane >> 4;
    const int l16  = lane & 15;

    // staging indices
    const int ar = t >> 4;   // 0..31 (A row), 2 float4 per thread
    const int aq = t & 15;   // float4 within row half
    const int bn = t >> 2;   // 0..127 (B row), 4 uint4 per thread
    const int bq = t & 3;    // 32-u16 chunk within row

    const float* Ap = Amat + (size_t)(m0 + ar) * NN + kbeg + aq * 4;
    const u16*   Bp = BT   + (size_t)bn * NN + kbeg + bq * 32;

    // prologue: load tile 0 into registers
    float4 va0 = *(const float4*)(Ap);
    float4 va1 = *(const float4*)(Ap + 64);
    uint4  vb0 = *(const uint4*)(Bp);
    uint4  vb1 = *(const uint4*)(Bp + 8);
    uint4  vb2 = *(const uint4*)(Bp + 16);
    uint4  vb3 = *(const uint4*)(Bp + 24);

    f32x4 acc0 = {0.f, 0.f, 0.f, 0.f};
    f32x4 acc1 = {0.f, 0.f, 0.f, 0.f};

    for (int kk = 0; kk < KPER; kk += BK) {
        // ---- store staged registers to LDS (vmcnt wait lands here) ----
        ushort4 u0, u1;
        u0.x = f2bf(va0.x); u0.y = f2bf(va0.y); u0.z = f2bf(va0.z); u0.w = f2bf(va0.w);
        u1.x = f2bf(va1.x); u1.y = f2bf(va1.y); u1.z = f2bf(va1.z); u1.w = f2bf(va1.w);
        *(ushort4*)&As[ar * LDK + aq * 4]      = u0;
        *(ushort4*)&As[ar * LDK + aq * 4 + 64] = u1;
        *(uint4*)&Bs[bn * LDK + bq * 32]      = vb0;
        *(uint4*)&Bs[bn * LDK + bq * 32 + 8]  = vb1;
        *(uint4*)&Bs[bn * LDK + bq * 32 + 16] = vb2;
        *(uint4*)&Bs[bn * LDK + bq * 32 + 24] = vb3;
        __syncthreads();

        // ---- issue next tile's global loads (overlap with MFMA below) ----
        if (kk + BK < KPER) {
            int k1 = kk + BK;
            va0 = *(const float4*)(Ap + k1);
            va1 = *(const float4*)(Ap + k1 + 64);
            vb0 = *(const uint4*)(Bp + k1);
            vb1 = *(const uint4*)(Bp + k1 + 8);
            vb2 = *(const uint4*)(Bp + k1 + 16);
            vb3 = *(const uint4*)(Bp + k1 + 24);
        }

        // ---- compute current tile from LDS ----
#pragma unroll
        for (int k2 = 0; k2 < 4; ++k2) {
            bf16x8 a0 = *(const bf16x8*)&As[l16 * LDK + k2 * 32 + quad * 8];
            bf16x8 a1 = *(const bf16x8*)&As[(16 + l16) * LDK + k2 * 32 + quad * 8];
            bf16x8 b  = *(const bf16x8*)&Bs[(wave * 16 + l16) * LDK + k2 * 32 + quad * 8];
            acc0 = __builtin_amdgcn_mfma_f32_16x16x32_bf16(a0, b, acc0, 0, 0, 0);
            acc1 = __builtin_amdgcn_mfma_f32_16x16x32_bf16(a1, b, acc1, 0, 0, 0);
        }
        __syncthreads();
    }

    // D layout: col = lane&15 (within wave's 16-col tile), row = quad*4+reg
    float* P = part + (size_t)ks * NN * DD;
#pragma unroll
    for (int r = 0; r < 4; ++r) {
        int row0 = m0 + quad * 4 + r;
        int col  = wave * 16 + l16;
        P[(size_t)row0 * DD + col]        = acc0[r];
        P[(size_t)(row0 + 16) * DD + col] = acc1[r];
    }
}

// ---------------------------------------------------------------------------
// feat = sum of KS partials
// ---------------------------------------------------------------------------
__global__ __launch_bounds__(256) void combine_feat(
    const float* __restrict__ part, float* __restrict__ feat)
{
    int i = blockIdx.x * 256 + threadIdx.x;   // float4 index, NN*DD/4 total
    const float4* p = (const float4*)part;
    const int S = NN * DD / 4;
    float4 a = p[i], b = p[i + S], c = p[i + 2 * S], d = p[i + 3 * S];
    float4 s;
    s.x = (a.x + b.x) + (c.x + d.x);
    s.y = (a.y + b.y) + (c.y + d.y);
    s.z = (a.z + b.z) + (c.z + d.z);
    s.w = (a.w + b.w) + (c.w + d.w);
    ((float4*)feat)[i] = s;
}

// ---------------------------------------------------------------------------
// out = (sum of KS partials) / (normsum[row] + EPS) + feat
// (rnorm kernel folded in: the rcp is 32x redundant per row but free)
// ---------------------------------------------------------------------------
__global__ __launch_bounds__(256) void combine_out(
    const float* __restrict__ part, const float* __restrict__ normsum,
    const float* __restrict__ feat, float* __restrict__ out)
{
    int i = blockIdx.x * 256 + threadIdx.x;   // float4 index
    int row = i >> 5;                          // 32 float4 per 128-col row
    const float4* p = (const float4*)part;
    const int S = NN * DD / 4;
    float4 a = p[i], b = p[i + S], c = p[i + 2 * S], d = p[i + 3 * S];
    float sc = 1.0f / (normsum[row] + EPS);
    float4 f = ((const float4*)feat)[i];
    float4 s;
    s.x = ((a.x + b.x) + (c.x + d.x)) * sc + f.x;
    s.y = ((a.y + b.y) + (c.y + d.y)) * sc + f.y;
    s.z = ((a.z + b.z) + (c.z + d.z)) * sc + f.z;
    s.w = ((a.w + b.w) + (c.w + d.w)) * sc + f.w;
    ((float4*)out)[i] = s;
}

// ---------------------------------------------------------------------------
extern "C" void kernel_launch(void* const* d_in, const int* in_sizes, int n_in,
                              void* d_out, int out_size, void* d_ws, size_t ws_size,
                              hipStream_t stream)
{
    const int*   currents = (const int*)d_in[0];
    const int*   targets  = (const int*)d_in[1];
    const float* acts     = (const float*)d_in[2];   // [4096][128]
    const float* cases    = (const float*)d_in[3];   // [E][128]
    const float* W        = (const float*)d_in[4];   // [4096][4096]
    float*       out      = (float*)d_out;           // [4096][128]
    const int E = in_sizes[0];

    // workspace layout
    char* ws = (char*)d_ws;
    float* att     = (float*)ws;                                     // 64 MB
    float* part    = (float*)(ws + (size_t)NN * NN * 4);             // KS*2 MB
    float* feat    = part + (size_t)KS * NN * DD;                    // 2 MB
    u16*   BT1     = (u16*)(feat + (size_t)NN * DD);                 // 1 MB
    u16*   BT2     = BT1 + (size_t)DD * NN;                          // 1 MB
    float* normsum = (float*)(BT2 + (size_t)DD * NN);                // 16 KB

    hipMemsetAsync(att, 0, (size_t)NN * NN * 4, stream);
    hipMemsetAsync(normsum, 0, (size_t)NN * 4, stream);

    // BT1 = bf16(acts^T)
    transpose_to_bf16<<<128, 256, 0, stream>>>(acts, BT1);

    // edge scatter (+ per-target norm accumulation)
    edge_kernel<<<(E + 7) / 8, 256, 0, stream>>>(currents, targets, acts, cases,
                                                 att, normsum, E);

    // feat = W @ acts  (split-K partials, then combine)
    gemm_splitk<<<dim3(NN / BM, KS), 512, 0, stream>>>(W, BT1, part);
    combine_feat<<<NN * DD / 4 / 256, 256, 0, stream>>>(part, feat);

    // BT2 = bf16(feat^T)
    transpose_to_bf16<<<128, 256, 0, stream>>>(feat, BT2);

    // out = (att @ feat) / norm + feat
    gemm_splitk<<<dim3(NN / BM, KS), 512, 0, stream>>>(att, BT2, part);
    combine_out<<<NN * DD / 4 / 256, 256, 0, stream>>>(part, normsum, feat, out);
}

// Round 2
// 214.869 us; speedup vs baseline: 1.1090x; 1.0874x over previous
//
#include <hip/hip_runtime.h>
#include <hip/hip_bf16.h>

typedef unsigned short u16;
typedef unsigned int   u32;

typedef __attribute__((ext_vector_type(8))) __bf16 bf16x8;
typedef __attribute__((ext_vector_type(4))) float  f32x4;

#define NN 4096
#define DD 128
#define EPS 1e-12f

#define KS 4            // split-K factor
#define BM 32           // rows per block
#define BK 128          // k per stage
#define KPER (NN / KS)  // 1024
#define LDK 136         // padded LDS row stride (u16), 272 B (16B-aligned)

static __device__ __forceinline__ u16 f2bf(float f) {
    union { float f; u32 u; } v; v.f = f;
    u32 r = v.u + 0x7fffu + ((v.u >> 16) & 1u);   // round-to-nearest-even
    return (u16)(r >> 16);
}

// ---------------------------------------------------------------------------
// Edge kernel: 32 lanes per edge (2 edges per wave).
// val = exp(-||A[c]+case-A[t]||); atomicAdd att[t*N+c] ONLY.
// (normsum is now computed as row-sums inside gemm #2 — the 1e6 atomics into
//  256 cache lines were suspected to serialize at the coherence point.)
// ---------------------------------------------------------------------------
__global__ __launch_bounds__(256) void edge_kernel(
    const int* __restrict__ currents, const int* __restrict__ targets,
    const float* __restrict__ A, const float* __restrict__ cases,
    float* __restrict__ att, int E)
{
    int e = blockIdx.x * 8 + (threadIdx.x >> 5);
    if (e >= E) return;
    int l = threadIdx.x & 31;
    int c = currents[e];
    int t = targets[e];
    float4 h = *(const float4*)(A + (size_t)c * DD + l * 4);
    float4 g = *(const float4*)(A + (size_t)t * DD + l * 4);
    float4 q = *(const float4*)(cases + (size_t)e * DD + l * 4);
    float d0 = h.x + q.x - g.x;
    float d1 = h.y + q.y - g.y;
    float d2 = h.z + q.z - g.z;
    float d3 = h.w + q.w - g.w;
    float s = d0 * d0 + d1 * d1 + d2 * d2 + d3 * d3;
#pragma unroll
    for (int m = 16; m; m >>= 1) s += __shfl_xor(s, m, 64);
    if (l == 0) {
        float val = __expf(-__fsqrt_rn(s));
        atomicAdd(att + (size_t)t * NN + c, val);
    }
}

// ---------------------------------------------------------------------------
// Transpose+convert: in [4096][128] fp32 -> out [128][4096] bf16
// ---------------------------------------------------------------------------
__global__ __launch_bounds__(256) void transpose_to_bf16(
    const float* __restrict__ in, u16* __restrict__ out)
{
    __shared__ __align__(16) u16 lds[128][40];
    const int k0 = blockIdx.x * 32;
    const int t = threadIdx.x;
#pragma unroll
    for (int i = 0; i < 4; ++i) {
        int f  = t + 256 * i;
        int kr = f >> 5;
        int n0 = (f & 31) * 4;
        float4 v = *(const float4*)(in + (size_t)(k0 + kr) * DD + n0);
        lds[n0 + 0][kr] = f2bf(v.x);
        lds[n0 + 1][kr] = f2bf(v.y);
        lds[n0 + 2][kr] = f2bf(v.z);
        lds[n0 + 3][kr] = f2bf(v.w);
    }
    __syncthreads();
    int n = t >> 1, h = t & 1;
    uint4 v0 = *(const uint4*)&lds[n][h * 16];
    uint4 v1 = *(const uint4*)&lds[n][h * 16 + 8];
    *(uint4*)(out + (size_t)n * NN + k0 + h * 16)     = v0;
    *(uint4*)(out + (size_t)n * NN + k0 + h * 16 + 8) = v1;
}

// ---------------------------------------------------------------------------
// Split-K skinny GEMM with 1-deep register pipeline:
//   part[ks] = Amat[m0:m0+32, ks*1024:(ks+1)*1024] @ B
// Amat fp32 (converted to bf16 in staging), BT bf16 [128][4096] (B^T).
// 512 threads = 8 waves; wave w covers n-cols w*16..w*16+15, both 16-row
// m-tiles. Grid (128, KS) -> 512 blocks = 2 blocks/CU, 16 waves/CU.
// ROWSUM: also accumulate fp32 row-sums of Amat into normsum (replaces the
// contended per-edge normsum atomics; ~4 atomics per address total).
// ---------------------------------------------------------------------------
template<bool ROWSUM>
__global__ __launch_bounds__(512, 4) void gemm_splitk(
    const float* __restrict__ Amat,   // [4096][4096]
    const u16*   __restrict__ BT,     // [128][4096]
    float* __restrict__ part,         // [KS][4096][128]
    float* __restrict__ normsum)      // [4096] (ROWSUM only)
{
    __shared__ __align__(16) u16 As[BM * LDK];   // 8.7 KB
    __shared__ __align__(16) u16 Bs[DD * LDK];   // 34.8 KB

    const int m0   = blockIdx.x * BM;
    const int ks   = blockIdx.y;
    const int kbeg = ks * KPER;
    const int t    = threadIdx.x;
    const int wave = t >> 6;
    const int lane = t & 63;
    const int quad = lane >> 4;
    const int l16  = lane & 15;

    // staging indices
    const int ar = t >> 4;   // 0..31 (A row), 2 float4 per thread
    const int aq = t & 15;   // float4 within row half
    const int bn = t >> 2;   // 0..127 (B row), 4 uint4 per thread
    const int bq = t & 3;    // 32-u16 chunk within row

    const float* Ap = Amat + (size_t)(m0 + ar) * NN + kbeg + aq * 4;
    const u16*   Bp = BT   + (size_t)bn * NN + kbeg + bq * 32;

    // prologue: load tile 0 into registers
    float4 va0 = *(const float4*)(Ap);
    float4 va1 = *(const float4*)(Ap + 64);
    uint4  vb0 = *(const uint4*)(Bp);
    uint4  vb1 = *(const uint4*)(Bp + 8);
    uint4  vb2 = *(const uint4*)(Bp + 16);
    uint4  vb3 = *(const uint4*)(Bp + 24);

    f32x4 acc0 = {0.f, 0.f, 0.f, 0.f};
    f32x4 acc1 = {0.f, 0.f, 0.f, 0.f};
    float rsum = 0.f;

    for (int kk = 0; kk < KPER; kk += BK) {
        // ---- store staged registers to LDS (vmcnt wait lands here) ----
        if (ROWSUM) {
            rsum += (va0.x + va0.y) + (va0.z + va0.w)
                  + (va1.x + va1.y) + (va1.z + va1.w);
        }
        ushort4 u0, u1;
        u0.x = f2bf(va0.x); u0.y = f2bf(va0.y); u0.z = f2bf(va0.z); u0.w = f2bf(va0.w);
        u1.x = f2bf(va1.x); u1.y = f2bf(va1.y); u1.z = f2bf(va1.z); u1.w = f2bf(va1.w);
        *(ushort4*)&As[ar * LDK + aq * 4]      = u0;
        *(ushort4*)&As[ar * LDK + aq * 4 + 64] = u1;
        *(uint4*)&Bs[bn * LDK + bq * 32]      = vb0;
        *(uint4*)&Bs[bn * LDK + bq * 32 + 8]  = vb1;
        *(uint4*)&Bs[bn * LDK + bq * 32 + 16] = vb2;
        *(uint4*)&Bs[bn * LDK + bq * 32 + 24] = vb3;
        __syncthreads();

        // ---- issue next tile's global loads (overlap with MFMA below) ----
        if (kk + BK < KPER) {
            int k1 = kk + BK;
            va0 = *(const float4*)(Ap + k1);
            va1 = *(const float4*)(Ap + k1 + 64);
            vb0 = *(const uint4*)(Bp + k1);
            vb1 = *(const uint4*)(Bp + k1 + 8);
            vb2 = *(const uint4*)(Bp + k1 + 16);
            vb3 = *(const uint4*)(Bp + k1 + 24);
        }

        // ---- compute current tile from LDS ----
#pragma unroll
        for (int k2 = 0; k2 < 4; ++k2) {
            bf16x8 a0 = *(const bf16x8*)&As[l16 * LDK + k2 * 32 + quad * 8];
            bf16x8 a1 = *(const bf16x8*)&As[(16 + l16) * LDK + k2 * 32 + quad * 8];
            bf16x8 b  = *(const bf16x8*)&Bs[(wave * 16 + l16) * LDK + k2 * 32 + quad * 8];
            acc0 = __builtin_amdgcn_mfma_f32_16x16x32_bf16(a0, b, acc0, 0, 0, 0);
            acc1 = __builtin_amdgcn_mfma_f32_16x16x32_bf16(a1, b, acc1, 0, 0, 0);
        }
        __syncthreads();
    }

    // D layout: col = lane&15 (within wave's 16-col tile), row = quad*4+reg
    float* P = part + (size_t)ks * NN * DD;
#pragma unroll
    for (int r = 0; r < 4; ++r) {
        int row0 = m0 + quad * 4 + r;
        int col  = wave * 16 + l16;
        P[(size_t)row0 * DD + col]        = acc0[r];
        P[(size_t)(row0 + 16) * DD + col] = acc1[r];
    }

    if (ROWSUM) {
        // 16 threads (t&15 = 0..15) share row ar; reduce within the quarter-wave
#pragma unroll
        for (int m = 8; m; m >>= 1) rsum += __shfl_xor(rsum, m, 64);
        if ((t & 15) == 0) atomicAdd(normsum + m0 + ar, rsum);
    }
}

// ---------------------------------------------------------------------------
// feat = sum of KS partials
// ---------------------------------------------------------------------------
__global__ __launch_bounds__(256) void combine_feat(
    const float* __restrict__ part, float* __restrict__ feat)
{
    int i = blockIdx.x * 256 + threadIdx.x;   // float4 index, NN*DD/4 total
    const float4* p = (const float4*)part;
    const int S = NN * DD / 4;
    float4 a = p[i], b = p[i + S], c = p[i + 2 * S], d = p[i + 3 * S];
    float4 s;
    s.x = (a.x + b.x) + (c.x + d.x);
    s.y = (a.y + b.y) + (c.y + d.y);
    s.z = (a.z + b.z) + (c.z + d.z);
    s.w = (a.w + b.w) + (c.w + d.w);
    ((float4*)feat)[i] = s;
}

// ---------------------------------------------------------------------------
// out = (sum of KS partials) / (normsum[row] + EPS) + feat
// ---------------------------------------------------------------------------
__global__ __launch_bounds__(256) void combine_out(
    const float* __restrict__ part, const float* __restrict__ normsum,
    const float* __restrict__ feat, float* __restrict__ out)
{
    int i = blockIdx.x * 256 + threadIdx.x;   // float4 index
    int row = i >> 5;                          // 32 float4 per 128-col row
    const float4* p = (const float4*)part;
    const int S = NN * DD / 4;
    float4 a = p[i], b = p[i + S], c = p[i + 2 * S], d = p[i + 3 * S];
    float sc = 1.0f / (normsum[row] + EPS);
    float4 f = ((const float4*)feat)[i];
    float4 s;
    s.x = ((a.x + b.x) + (c.x + d.x)) * sc + f.x;
    s.y = ((a.y + b.y) + (c.y + d.y)) * sc + f.y;
    s.z = ((a.z + b.z) + (c.z + d.z)) * sc + f.z;
    s.w = ((a.w + b.w) + (c.w + d.w)) * sc + f.w;
    ((float4*)out)[i] = s;
}

// ---------------------------------------------------------------------------
extern "C" void kernel_launch(void* const* d_in, const int* in_sizes, int n_in,
                              void* d_out, int out_size, void* d_ws, size_t ws_size,
                              hipStream_t stream)
{
    const int*   currents = (const int*)d_in[0];
    const int*   targets  = (const int*)d_in[1];
    const float* acts     = (const float*)d_in[2];   // [4096][128]
    const float* cases    = (const float*)d_in[3];   // [E][128]
    const float* W        = (const float*)d_in[4];   // [4096][4096]
    float*       out      = (float*)d_out;           // [4096][128]
    const int E = in_sizes[0];

    // workspace layout
    char* ws = (char*)d_ws;
    float* att     = (float*)ws;                                     // 64 MB
    float* part    = (float*)(ws + (size_t)NN * NN * 4);             // KS*2 MB
    float* feat    = part + (size_t)KS * NN * DD;                    // 2 MB
    u16*   BT1     = (u16*)(feat + (size_t)NN * DD);                 // 1 MB
    u16*   BT2     = BT1 + (size_t)DD * NN;                          // 1 MB
    float* normsum = (float*)(BT2 + (size_t)DD * NN);                // 16 KB

    hipMemsetAsync(att, 0, (size_t)NN * NN * 4, stream);
    hipMemsetAsync(normsum, 0, (size_t)NN * 4, stream);

    // BT1 = bf16(acts^T)
    transpose_to_bf16<<<128, 256, 0, stream>>>(acts, BT1);

    // edge scatter (att only; no normsum atomics)
    edge_kernel<<<(E + 7) / 8, 256, 0, stream>>>(currents, targets, acts, cases,
                                                 att, E);

    // feat = W @ acts  (split-K partials, then combine)
    gemm_splitk<false><<<dim3(NN / BM, KS), 512, 0, stream>>>(W, BT1, part, nullptr);
    combine_feat<<<NN * DD / 4 / 256, 256, 0, stream>>>(part, feat);

    // BT2 = bf16(feat^T)
    transpose_to_bf16<<<128, 256, 0, stream>>>(feat, BT2);

    // out = (att @ feat) / norm + feat   (gemm #2 also produces norm row-sums)
    gemm_splitk<true><<<dim3(NN / BM, KS), 512, 0, stream>>>(att, BT2, part, normsum);
    combine_out<<<NN * DD / 4 / 256, 256, 0, stream>>>(part, normsum, feat, out);
}

// Round 3
// 197.506 us; speedup vs baseline: 1.2065x; 1.0879x over previous
//
#include <hip/hip_runtime.h>
#include <hip/hip_bf16.h>

typedef unsigned short u16;
typedef unsigned int   u32;

typedef __attribute__((ext_vector_type(8))) __bf16 bf16x8;
typedef __attribute__((ext_vector_type(4))) float  f32x4;
typedef __attribute__((ext_vector_type(4))) u32    u32x4;

#define NN 4096
#define DD 128
#define EPS 1e-12f

#define KS 4            // split-K factor
#define BM 32           // rows per block
#define BK 128          // k per stage
#define KPER (NN / KS)  // 1024
#define LDK 136         // padded LDS row stride (u16), 272 B (16B-aligned)

static __device__ __forceinline__ u16 f2bf(float f) {
    union { float f; u32 u; } v; v.f = f;
    u32 r = v.u + 0x7fffu + ((v.u >> 16) & 1u);   // round-to-nearest-even
    return (u16)(r >> 16);
}
static __device__ __forceinline__ float bf2f(u16 u) {
    union { u32 i; float f; } v; v.i = (u32)u << 16; return v.f;
}

// --- bf16x2 atomic add: HW pk_add_bf16 if available, CAS fallback otherwise ---
template <typename T>
static __device__ __forceinline__ auto bf2_atomic_add(T* p, T v, int)
    -> decltype(unsafeAtomicAdd(p, v), void()) {
    unsafeAtomicAdd(p, v);
}
template <typename T>
static __device__ __forceinline__ void bf2_atomic_add(T* p, T v, long) {
    u32* w = (u32*)p;
    union { u32 i; T h; } av; av.h = v;
    float alo = bf2f((u16)(av.i & 0xffff));
    float ahi = bf2f((u16)(av.i >> 16));
    u32 old = *w, assumed;
    do {
        assumed = old;
        float lo = bf2f((u16)(assumed & 0xffff)) + alo;
        float hi = bf2f((u16)(assumed >> 16)) + ahi;
        u32 nv = (u32)f2bf(lo) | ((u32)f2bf(hi) << 16);
        old = atomicCAS(w, assumed, nv);
    } while (old != assumed);
}

// ---------------------------------------------------------------------------
// Edge kernel: 32 lanes per edge (2 edges per wave).
// val = exp(-||A[c]+case-A[t]||); packed-bf16 atomicAdd into att[t*N+c].
// cases is read-once 512 MB -> non-temporal (keep att/A resident in L2/L3).
// ---------------------------------------------------------------------------
__global__ __launch_bounds__(256) void edge_kernel(
    const int* __restrict__ currents, const int* __restrict__ targets,
    const float* __restrict__ A, const float* __restrict__ cases,
    u16* __restrict__ att, int E)
{
    int e = blockIdx.x * 8 + (threadIdx.x >> 5);
    if (e >= E) return;
    int l = threadIdx.x & 31;
    int c = currents[e];
    int t = targets[e];
    f32x4 h = *(const f32x4*)(A + (size_t)c * DD + l * 4);
    f32x4 g = *(const f32x4*)(A + (size_t)t * DD + l * 4);
    f32x4 q = __builtin_nontemporal_load((const f32x4*)(cases + (size_t)e * DD + l * 4));
    float d0 = h.x + q.x - g.x;
    float d1 = h.y + q.y - g.y;
    float d2 = h.z + q.z - g.z;
    float d3 = h.w + q.w - g.w;
    float s = d0 * d0 + d1 * d1 + d2 * d2 + d3 * d3;
#pragma unroll
    for (int m = 16; m; m >>= 1) s += __shfl_xor(s, m, 64);
    if (l == 0) {
        float val = __expf(-__fsqrt_rn(s));
        u16 b = f2bf(val);
        size_t off = (size_t)t * NN + c;
        union { u32 i; __hip_bfloat162 h2; } pk;
        pk.i = (c & 1) ? ((u32)b << 16) : (u32)b;
        bf2_atomic_add((__hip_bfloat162*)(att + (off & ~(size_t)1)), pk.h2, 0);
    }
}

// ---------------------------------------------------------------------------
// Transpose+convert: in [4096][128] fp32 -> out [128][4096] bf16
// ---------------------------------------------------------------------------
__global__ __launch_bounds__(256) void transpose_to_bf16(
    const float* __restrict__ in, u16* __restrict__ out)
{
    __shared__ __align__(16) u16 lds[128][40];
    const int k0 = blockIdx.x * 32;
    const int t = threadIdx.x;
#pragma unroll
    for (int i = 0; i < 4; ++i) {
        int f  = t + 256 * i;
        int kr = f >> 5;
        int n0 = (f & 31) * 4;
        float4 v = *(const float4*)(in + (size_t)(k0 + kr) * DD + n0);
        lds[n0 + 0][kr] = f2bf(v.x);
        lds[n0 + 1][kr] = f2bf(v.y);
        lds[n0 + 2][kr] = f2bf(v.z);
        lds[n0 + 3][kr] = f2bf(v.w);
    }
    __syncthreads();
    int n = t >> 1, h = t & 1;
    uint4 v0 = *(const uint4*)&lds[n][h * 16];
    uint4 v1 = *(const uint4*)&lds[n][h * 16 + 8];
    *(uint4*)(out + (size_t)n * NN + k0 + h * 16)     = v0;
    *(uint4*)(out + (size_t)n * NN + k0 + h * 16 + 8) = v1;
}

// ---------------------------------------------------------------------------
// Split-K skinny GEMM with 1-deep register pipeline:
//   part[ks] = Amat[m0:m0+32, ks*1024:(ks+1)*1024] @ B
// ABF16=false: Amat fp32 (W), converted to bf16 in staging.
// ABF16=true : Amat bf16 (att), staged directly.
// A-panel is read-once -> non-temporal loads.
// ROWSUM: accumulate fp32 row-sums of Amat into normsum (atomic, 4/addr).
// ---------------------------------------------------------------------------
template<bool ROWSUM, bool ABF16>
__global__ __launch_bounds__(512, 4) void gemm_splitk(
    const void* __restrict__ AmatV,
    const u16*  __restrict__ BT,      // [128][4096] bf16 (B^T)
    float* __restrict__ part,         // [KS][4096][128]
    float* __restrict__ normsum)      // [4096] (ROWSUM only)
{
    __shared__ __align__(16) u16 As[BM * LDK];   // 8.7 KB
    __shared__ __align__(16) u16 Bs[DD * LDK];   // 34.8 KB

    const int m0   = blockIdx.x * BM;
    const int ks   = blockIdx.y;
    const int kbeg = ks * KPER;
    const int t    = threadIdx.x;
    const int wave = t >> 6;
    const int lane = t & 63;
    const int quad = lane >> 4;
    const int l16  = lane & 15;

    // staging indices
    const int ar = t >> 4;   // 0..31 (A row)
    const int aq = t & 15;   // chunk within row
    const int bn = t >> 2;   // 0..127 (B row)
    const int bq = t & 3;    // 32-u16 chunk within row

    const float* Apf = (const float*)AmatV + (size_t)(m0 + ar) * NN + kbeg + aq * 4;
    const u16*   Aph = (const u16*)AmatV   + (size_t)(m0 + ar) * NN + kbeg + aq * 8;
    const u16*   Bp  = BT + (size_t)bn * NN + kbeg + bq * 32;

    // prologue: load tile 0 into registers
    f32x4 va0, va1; u32x4 vah;
    if constexpr (ABF16) {
        vah = __builtin_nontemporal_load((const u32x4*)Aph);
    } else {
        va0 = __builtin_nontemporal_load((const f32x4*)Apf);
        va1 = __builtin_nontemporal_load((const f32x4*)(Apf + 64));
    }
    uint4 vb0 = *(const uint4*)(Bp);
    uint4 vb1 = *(const uint4*)(Bp + 8);
    uint4 vb2 = *(const uint4*)(Bp + 16);
    uint4 vb3 = *(const uint4*)(Bp + 24);

    f32x4 acc0 = {0.f, 0.f, 0.f, 0.f};
    f32x4 acc1 = {0.f, 0.f, 0.f, 0.f};
    float rsum = 0.f;

    for (int kk = 0; kk < KPER; kk += BK) {
        // ---- store staged registers to LDS (vmcnt wait lands here) ----
        if constexpr (ABF16) {
            if (ROWSUM) {
#pragma unroll
            for (int j = 0; j < 4; ++j) {
                u32 w = vah[j];
                rsum += bf2f((u16)(w & 0xffff)) + bf2f((u16)(w >> 16));
            }
            }
            *(u32x4*)&As[ar * LDK + aq * 8] = vah;
        } else {
            if (ROWSUM) {
                rsum += (va0.x + va0.y) + (va0.z + va0.w)
                      + (va1.x + va1.y) + (va1.z + va1.w);
            }
            ushort4 u0, u1;
            u0.x = f2bf(va0.x); u0.y = f2bf(va0.y); u0.z = f2bf(va0.z); u0.w = f2bf(va0.w);
            u1.x = f2bf(va1.x); u1.y = f2bf(va1.y); u1.z = f2bf(va1.z); u1.w = f2bf(va1.w);
            *(ushort4*)&As[ar * LDK + aq * 4]      = u0;
            *(ushort4*)&As[ar * LDK + aq * 4 + 64] = u1;
        }
        *(uint4*)&Bs[bn * LDK + bq * 32]      = vb0;
        *(uint4*)&Bs[bn * LDK + bq * 32 + 8]  = vb1;
        *(uint4*)&Bs[bn * LDK + bq * 32 + 16] = vb2;
        *(uint4*)&Bs[bn * LDK + bq * 32 + 24] = vb3;
        __syncthreads();

        // ---- issue next tile's global loads (overlap with MFMA below) ----
        if (kk + BK < KPER) {
            int k1 = kk + BK;
            if constexpr (ABF16) {
                vah = __builtin_nontemporal_load((const u32x4*)(Aph + k1));
            } else {
                va0 = __builtin_nontemporal_load((const f32x4*)(Apf + k1));
                va1 = __builtin_nontemporal_load((const f32x4*)(Apf + k1 + 64));
            }
            vb0 = *(const uint4*)(Bp + k1);
            vb1 = *(const uint4*)(Bp + k1 + 8);
            vb2 = *(const uint4*)(Bp + k1 + 16);
            vb3 = *(const uint4*)(Bp + k1 + 24);
        }

        // ---- compute current tile from LDS ----
#pragma unroll
        for (int k2 = 0; k2 < 4; ++k2) {
            bf16x8 a0 = *(const bf16x8*)&As[l16 * LDK + k2 * 32 + quad * 8];
            bf16x8 a1 = *(const bf16x8*)&As[(16 + l16) * LDK + k2 * 32 + quad * 8];
            bf16x8 b  = *(const bf16x8*)&Bs[(wave * 16 + l16) * LDK + k2 * 32 + quad * 8];
            acc0 = __builtin_amdgcn_mfma_f32_16x16x32_bf16(a0, b, acc0, 0, 0, 0);
            acc1 = __builtin_amdgcn_mfma_f32_16x16x32_bf16(a1, b, acc1, 0, 0, 0);
        }
        __syncthreads();
    }

    // D layout: col = lane&15 (within wave's 16-col tile), row = quad*4+reg
    float* P = part + (size_t)ks * NN * DD;
#pragma unroll
    for (int r = 0; r < 4; ++r) {
        int row0 = m0 + quad * 4 + r;
        int col  = wave * 16 + l16;
        P[(size_t)row0 * DD + col]        = acc0[r];
        P[(size_t)(row0 + 16) * DD + col] = acc1[r];
    }

    if (ROWSUM) {
        // 16 threads (aq = 0..15) share row ar; reduce within the 16-lane group
#pragma unroll
        for (int m = 8; m; m >>= 1) rsum += __shfl_xor(rsum, m, 64);
        if ((t & 15) == 0) atomicAdd(normsum + m0 + ar, rsum);
    }
}

// ---------------------------------------------------------------------------
// feat = sum of KS partials
// ---------------------------------------------------------------------------
__global__ __launch_bounds__(256) void combine_feat(
    const float* __restrict__ part, float* __restrict__ feat)
{
    int i = blockIdx.x * 256 + threadIdx.x;   // float4 index, NN*DD/4 total
    const float4* p = (const float4*)part;
    const int S = NN * DD / 4;
    float4 a = p[i], b = p[i + S], c = p[i + 2 * S], d = p[i + 3 * S];
    float4 s;
    s.x = (a.x + b.x) + (c.x + d.x);
    s.y = (a.y + b.y) + (c.y + d.y);
    s.z = (a.z + b.z) + (c.z + d.z);
    s.w = (a.w + b.w) + (c.w + d.w);
    ((float4*)feat)[i] = s;
}

// ---------------------------------------------------------------------------
// out = (sum of KS partials) / (normsum[row] + EPS) + feat
// ---------------------------------------------------------------------------
__global__ __launch_bounds__(256) void combine_out(
    const float* __restrict__ part, const float* __restrict__ normsum,
    const float* __restrict__ feat, float* __restrict__ out)
{
    int i = blockIdx.x * 256 + threadIdx.x;   // float4 index
    int row = i >> 5;                          // 32 float4 per 128-col row
    const float4* p = (const float4*)part;
    const int S = NN * DD / 4;
    float4 a = p[i], b = p[i + S], c = p[i + 2 * S], d = p[i + 3 * S];
    float sc = 1.0f / (normsum[row] + EPS);
    float4 f = ((const float4*)feat)[i];
    float4 s;
    s.x = ((a.x + b.x) + (c.x + d.x)) * sc + f.x;
    s.y = ((a.y + b.y) + (c.y + d.y)) * sc + f.y;
    s.z = ((a.z + b.z) + (c.z + d.z)) * sc + f.z;
    s.w = ((a.w + b.w) + (c.w + d.w)) * sc + f.w;
    ((float4*)out)[i] = s;
}

// ---------------------------------------------------------------------------
extern "C" void kernel_launch(void* const* d_in, const int* in_sizes, int n_in,
                              void* d_out, int out_size, void* d_ws, size_t ws_size,
                              hipStream_t stream)
{
    const int*   currents = (const int*)d_in[0];
    const int*   targets  = (const int*)d_in[1];
    const float* acts     = (const float*)d_in[2];   // [4096][128]
    const float* cases    = (const float*)d_in[3];   // [E][128]
    const float* W        = (const float*)d_in[4];   // [4096][4096]
    float*       out      = (float*)d_out;           // [4096][128]
    const int E = in_sizes[0];

    // workspace layout
    char* ws = (char*)d_ws;
    u16*   att     = (u16*)ws;                                       // 32 MB (bf16)
    float* part    = (float*)(ws + (size_t)NN * NN * 2);             // KS*2 MB
    float* feat    = part + (size_t)KS * NN * DD;                    // 2 MB
    u16*   BT1     = (u16*)(feat + (size_t)NN * DD);                 // 1 MB
    u16*   BT2     = BT1 + (size_t)DD * NN;                          // 1 MB
    float* normsum = (float*)(BT2 + (size_t)DD * NN);                // 16 KB

    hipMemsetAsync(att, 0, (size_t)NN * NN * 2, stream);
    hipMemsetAsync(normsum, 0, (size_t)NN * 4, stream);

    // BT1 = bf16(acts^T)
    transpose_to_bf16<<<128, 256, 0, stream>>>(acts, BT1);

    // edge scatter (packed-bf16 atomics into bf16 att)
    edge_kernel<<<(E + 7) / 8, 256, 0, stream>>>(currents, targets, acts, cases,
                                                 att, E);

    // feat = W @ acts  (split-K partials, then combine)
    gemm_splitk<false, false><<<dim3(NN / BM, KS), 512, 0, stream>>>(W, BT1, part, nullptr);
    combine_feat<<<NN * DD / 4 / 256, 256, 0, stream>>>(part, feat);

    // BT2 = bf16(feat^T)
    transpose_to_bf16<<<128, 256, 0, stream>>>(feat, BT2);

    // out = (att @ feat) / norm + feat   (gemm #2 also produces norm row-sums)
    gemm_splitk<true, true><<<dim3(NN / BM, KS), 512, 0, stream>>>(att, BT2, part, normsum);
    combine_out<<<NN * DD / 4 / 256, 256, 0, stream>>>(part, normsum, feat, out);
}